// Round 1
// 836.213 us; speedup vs baseline: 1.3519x; 1.3519x over previous
//
#include <hip/hip_runtime.h>
#include <math.h>

typedef _Float16 half8 __attribute__((ext_vector_type(8)));
typedef float float4v __attribute__((ext_vector_type(4)));

#define SELU_ALPHA 1.6732632423543772f
#define SELU_SCALE 1.0507009873554805f

__device__ __forceinline__ float selu_f(float x) {
    return x > 0.f ? SELU_SCALE * x : SELU_SCALE * SELU_ALPHA * (__expf(x) - 1.f);
}
__device__ __forceinline__ float gate_f(float a, float sc, float sh) {
    // BN (pre-folded) -> SELU -> sigmoid
    float z = a * sc + sh;
    float s = selu_f(z);
    return 1.f / (1.f + __expf(-s));
}

// One-time prep:
//  - cast pw_w to f16 (layout [c4][cc], MFMA-B friendly)
//  - fold BN2 into scale/shift
//  - pack per-channel dw data: 9 weights + BN1 scale + BN1 shift + pad = 12 f
//    (16B-aligned so the cell kernel reads 3x float4 per channel)
// threads: 32768 (wB) + 256 (bn2) + 1536 (dwpk) = 34560 = 135 * 256
__global__ __launch_bounds__(256) void prep_kernel(
    const float* __restrict__ pw_w,
    const float* __restrict__ g1, const float* __restrict__ b1,
    const float* __restrict__ m1, const float* __restrict__ v1,
    const float* __restrict__ g2, const float* __restrict__ b2,
    const float* __restrict__ m2, const float* __restrict__ v2,
    const float* __restrict__ dw_w,
    _Float16* __restrict__ wB, float* __restrict__ bn2, float* __restrict__ dwpk)
{
    int i = blockIdx.x * 256 + threadIdx.x;
    if (i < 32768) {
        wB[i] = (_Float16)pw_w[i];
    } else if (i < 32768 + 256) {
        int c = i - 32768;
        float sc = g2[c] * rsqrtf(v2[c] + 1e-5f);
        bn2[c] = sc;
        bn2[256 + c] = b2[c] - m2[c] * sc;
    } else if (i < 32768 + 256 + 1536) {
        int j = i - 33024;
        int c = j / 12, k = j - c * 12;
        float val;
        if (k < 9) {
            val = dw_w[c * 9 + k];
        } else {
            float sc = g1[c] * rsqrtf(v1[c] + 1e-5f);
            if (k == 9) val = sc;
            else if (k == 10) val = b1[c] - m1[c] * sc;
            else val = 0.f;
        }
        dwpk[c * 12 + k] = val;
    }
}

// Fused ConvLSTM cell for one timestep.
// Block = one y-row (64 px) of one batch. grid 64x8 = 512 blocks = 2/CU.
// Phase 1: depthwise 3x3 + BN1 + SELU straight into the LDS A-tile
//   (wave w owns channels [32w, 32w+32); lane = x pixel; 3 coalesced row
//    loads per channel; 3x3 factored into column sums P/Q/R so the x-taps
//    cost only 2 shuffles per channel)
// Phase 2: MFMA GEMM (M=64 px, N=256 gates, K=128) + BN2 + SELU + sigmoid
//    + LSTM state update (unchanged from the previous pw_kernel).
__global__ __launch_bounds__(256, 2) void cell_kernel(
    const float* __restrict__ x, const float* __restrict__ hsrc,
    const float* __restrict__ dwpk, const _Float16* __restrict__ wB,
    const float* __restrict__ bn2,
    float* __restrict__ cbuf, float* __restrict__ out, int t)
{
    // A tile: [64 s][128 cc] f16, pitch 136 halves (row stride 272B = 16B
    // aligned for ds_read_b128; 2-way bank aliasing on reads = free)
    __shared__ _Float16 Alds[64 * 136];

    int tid = threadIdx.x;
    // XCD swizzle: linear block id -> (xcd = bid&7) gets a contiguous chunk.
    // 512 blocks = 8 xcd * 64: each XCD owns exactly one batch b, so h halo,
    // x_t and cbuf for that batch stay in its 4MB L2 across the sequence.
    int bid = blockIdx.y * 64 + blockIdx.x;
    int mapped = (bid & 7) * 64 + (bid >> 3);
    int y0 = mapped & 63;
    int b = mapped >> 6;
    int s0 = y0 << 6;

    int w = tid >> 6;
    int lane = tid & 63;
    int col = lane & 15, quad = lane >> 4;
    int hc = w * 16 + col;

    // ---- preload weight (B) fragments into registers: 16 x 16B per lane ----
    half8 bfr[4][4];   // [nt gate][kc]
    #pragma unroll
    for (int nt = 0; nt < 4; ++nt)
        #pragma unroll
        for (int kc = 0; kc < 4; ++kc)
            bfr[nt][kc] = *(const half8*)(wB + (size_t)((nt << 6) + hc) * 128 + kc * 32 + quad * 8);

    // ---- depthwise phase: wave w -> channels [32w, 32w+32), 2 per iter ----
    bool hwave = (w >= 2);
    const float* src0;
    if (!hwave)
        src0 = x + (((size_t)(b * 20 + t) * 64 + (w << 5)) << 12);
    else
        src0 = hsrc + (((size_t)(b * 20 + (t - 1)) * 64 + ((w - 2) << 5)) << 12);

    if (hwave && t == 0) {
        // h == 0: conv output is 0, z = BN1 shift only
        #pragma unroll
        for (int it = 0; it < 16; ++it) {
            int cc = (w << 5) + (it << 1);
            float sha = dwpk[cc * 12 + 10];
            float shb = dwpk[cc * 12 + 22];
            Alds[lane * 136 + cc]     = (_Float16)selu_f(sha);
            Alds[lane * 136 + cc + 1] = (_Float16)selu_f(shb);
        }
    } else {
        #pragma unroll 4
        for (int it = 0; it < 16; ++it) {
            int cl = it << 1;                 // local channel 0,2,..,30
            int cc = (w << 5) + cl;           // global cc (even)
            const float* chA = src0 + ((size_t)cl << 12);
            const float* chB = chA + 4096;
            int p = s0 + lane;
            float a0 = (y0 > 0)  ? chA[p - 64] : 0.f;
            float a1 = chA[p];
            float a2 = (y0 < 63) ? chA[p + 64] : 0.f;
            float c0 = (y0 > 0)  ? chB[p - 64] : 0.f;
            float c1 = chB[p];
            float c2 = (y0 < 63) ? chB[p + 64] : 0.f;
            const float4v* wp = (const float4v*)(dwpk + cc * 12);
            float4v wa0 = wp[0], wa1 = wp[1], wa2 = wp[2];   // ch A: w00..w22, sc, sh
            float4v wb0 = wp[3], wb1 = wp[4], wb2 = wp[5];   // ch B
            // column sums: P = kx0 taps, Q = kx1, R = kx2
            float P  = fmaf(wa0[0], a0, fmaf(wa0[3], a1, wa1[2] * a2));
            float Q  = fmaf(wa0[1], a0, fmaf(wa1[0], a1, wa1[3] * a2));
            float R  = fmaf(wa0[2], a0, fmaf(wa1[1], a1, wa2[0] * a2));
            float P2 = fmaf(wb0[0], c0, fmaf(wb0[3], c1, wb1[2] * c2));
            float Q2 = fmaf(wb0[1], c0, fmaf(wb1[0], c1, wb1[3] * c2));
            float R2 = fmaf(wb0[2], c0, fmaf(wb1[1], c1, wb2[0] * c2));
            float Pl  = __shfl_up(P, 1);    if (lane == 0)  Pl  = 0.f;
            float Rr  = __shfl_down(R, 1);  if (lane == 63) Rr  = 0.f;
            float P2l = __shfl_up(P2, 1);   if (lane == 0)  P2l = 0.f;
            float R2r = __shfl_down(R2, 1); if (lane == 63) R2r = 0.f;
            float za = fmaf(Pl + Q + Rr,   wa2[1], wa2[2]);
            float zb = fmaf(P2l + Q2 + R2r, wb2[1], wb2[2]);
            Alds[lane * 136 + cc]     = (_Float16)selu_f(za);
            Alds[lane * 136 + cc + 1] = (_Float16)selu_f(zb);
        }
    }

    __syncthreads();

    // ---- MFMA main: 4 kc x (4 mt A-frags from LDS, 16 mfmas) ----
    float4v acc[4][4];
    #pragma unroll
    for (int mt = 0; mt < 4; ++mt)
        #pragma unroll
        for (int nt = 0; nt < 4; ++nt)
            acc[mt][nt] = (float4v){0.f, 0.f, 0.f, 0.f};

    #pragma unroll
    for (int kc = 0; kc < 4; ++kc) {
        half8 a[4];
        #pragma unroll
        for (int mt = 0; mt < 4; ++mt)
            a[mt] = *(const half8*)(Alds + (mt * 16 + col) * 136 + kc * 32 + quad * 8);
        #pragma unroll
        for (int mt = 0; mt < 4; ++mt)
            #pragma unroll
            for (int nt = 0; nt < 4; ++nt)
                acc[mt][nt] = __builtin_amdgcn_mfma_f32_16x16x32_f16(a[mt], bfr[nt][kc], acc[mt][nt], 0, 0, 0);
    }

    // ---- epilogue: BN2+SELU+sigmoid per gate, LSTM update ----
    float sc[4], sh[4];
    #pragma unroll
    for (int nt = 0; nt < 4; ++nt) {
        sc[nt] = bn2[(nt << 6) + hc];
        sh[nt] = bn2[256 + (nt << 6) + hc];
    }

    size_t cbase = (((size_t)(b * 64 + hc)) << 12) + s0;
    size_t obase = (((size_t)((b * 20 + t) * 64 + hc)) << 12) + s0;

    #pragma unroll
    for (int mt = 0; mt < 4; ++mt) {
        #pragma unroll
        for (int r = 0; r < 4; ++r) {
            int sl = mt * 16 + quad * 4 + r;
            float gi = gate_f(acc[mt][0][r], sc[0], sh[0]);
            float gf = gate_f(acc[mt][1][r], sc[1], sh[1]);
            float go = gate_f(acc[mt][2][r], sc[2], sh[2]);
            float gg = gate_f(acc[mt][3][r], sc[3], sh[3]);
            float cp = (t == 0) ? 0.f : cbuf[cbase + sl];
            float cn = gf * cp + gi * gg;
            cbuf[cbase + sl] = cn;
            // tanh via exp: tanh(x) = 1 - 2/(exp(2x)+1)
            float th = 1.f - 2.f / (__expf(2.f * cn) + 1.f);
            out[obase + sl] = go * th;
        }
    }
}

extern "C" void kernel_launch(void* const* d_in, const int* in_sizes, int n_in,
                              void* d_out, int out_size, void* d_ws, size_t ws_size,
                              hipStream_t stream) {
    const float* x    = (const float*)d_in[0];
    const float* dw_w = (const float*)d_in[1];
    const float* g1   = (const float*)d_in[2];
    const float* b1   = (const float*)d_in[3];
    const float* m1   = (const float*)d_in[4];
    const float* v1   = (const float*)d_in[5];
    const float* g2   = (const float*)d_in[6];
    const float* b2   = (const float*)d_in[7];
    const float* m2   = (const float*)d_in[8];
    const float* v2   = (const float*)d_in[9];
    const float* pw_w = (const float*)d_in[6 - 2 + 2]; // placeholder, fixed below
    (void)pw_w;
    // correct input order (matches reference signature):
    // x, dw_w, gamma1, beta1, mean1, var1, pw_w, gamma2, beta2, mean2, var2
    const float* pw_w_ = (const float*)d_in[6];
    const float* g2_   = (const float*)d_in[7];
    const float* b2_   = (const float*)d_in[8];
    const float* m2_   = (const float*)d_in[9];
    const float* v2_   = (const float*)d_in[10];
    float* out = (float*)d_out;

    // ws layout (floats): wB16 [32768 halves = 16384 f] | bn2 [512 f] |
    //                     dwpk [1536 f] | cbuf [8*64*4096 f]
    _Float16* wB16 = (_Float16*)d_ws;
    float* bn2  = (float*)d_ws + 16384;
    float* dwpk = bn2 + 512;
    float* cbuf = dwpk + 1536;

    prep_kernel<<<135, 256, 0, stream>>>(pw_w_, g1, b1, m1, v1,
                                         g2_, b2_, m2_, v2_, dw_w,
                                         wB16, bn2, dwpk);

    for (int t = 0; t < 20; ++t) {
        cell_kernel<<<dim3(64, 8), 256, 0, stream>>>(x, out, dwpk, wB16, bn2,
                                                     cbuf, out, t);
    }
}